// Round 11
// baseline (477.342 us; speedup 1.0000x reference)
//
#include <hip/hip_runtime.h>
#include <math.h>

#define NBR 4
#define NLAY 3
#define Bk 4
#define Tk 1024
#define DIN 32
#define DMODEL 128
#define DINNER 256
#define DSTATE 16
#define DTRANK 8
#define EMBEDk 64
#define BT (Bk*Tk)          /* 4096 rows per branch */
#define EPSF 1e-7f
#define MAXNF 10.0f
#define LCH 64              /* scan chunk length */
#define NCH (Tk/LCH)        /* 16 chunks */
#define UF 8                /* t-loop batch (latency amortization) */
#define NWB 320             /* dt|bc panel rows: 256 dt + 32 bc + 32 pad */

typedef __bf16 bf16x8 __attribute__((ext_vector_type(8)));
typedef float  f32x4  __attribute__((ext_vector_type(4)));
typedef unsigned short u16x8 __attribute__((ext_vector_type(8)));

__device__ __forceinline__ float siluf(float x){ return x / (1.f + __expf(-x)); }
__device__ __forceinline__ float softplusf(float x){ return (x > 20.f) ? x : log1pf(__expf(x)); }
__device__ __forceinline__ unsigned short f2b(float x){
    union { float f; unsigned u; } v; v.f = x;
    unsigned r = v.u + 0x7FFF + ((v.u >> 16) & 1);
    return (unsigned short)(r >> 16);
}
__device__ __forceinline__ float b2f(unsigned short u){
    union { unsigned u; float f; } v; v.u = ((unsigned)u) << 16; return v.f;
}

__device__ __forceinline__ void dA_pow(float q, float* dA){
    dA[0] = q;             dA[1] = q * q;
    dA[2] = dA[1] * dA[0]; dA[3] = dA[1] * dA[1];
    dA[4] = dA[3] * dA[0]; dA[5] = dA[3] * dA[1];
    dA[6] = dA[3] * dA[2]; dA[7] = dA[3] * dA[3];
    #pragma unroll
    for (int s = 8; s < 16; ++s) dA[s] = dA[s - 8] * dA[7];
}
__device__ __forceinline__ void dA_exp(float dtv, const float* Aa, float* dA){
    #pragma unroll
    for (int s = 0; s < 16; ++s) dA[s] = __expf(dtv * Aa[s]);
}

// ---------------------------------------------------------------------------
// bf16 MFMA GEMM: A bf16 [M][K]; B TRANSPOSED bf16 [N][K].  64x64 tile,
// 4 waves (32x32 quadrants, 2x2x2 mfma_f32_16x16x32_bf16), Kc=64.
// MODE 0 (xz):  col<256 -> Cb bf16 (xp); col>=256 -> Cb2 bf16 silu (z)
// MODE 1 (out): mean-reduce over rows -> atomicAdd into Mb[b][col]
// MODE 3 (dtbc): col<256 -> C0 softplus(v+bias) (dt f32 ld 256);
//                col 256..287 -> C1 f32 (bc ld 32); col>=288 dropped
// ---------------------------------------------------------------------------
template<int MODE>
__global__ __launch_bounds__(256) void bgemm_k(
    const unsigned short* __restrict__ Ab, long aBr, int K,
    const unsigned short* __restrict__ Bt, long bBr,
    float* __restrict__ C0, long c0Br,
    float* __restrict__ C1, long c1Br,
    unsigned short* __restrict__ Cb, long cbBr,
    unsigned short* __restrict__ Cb2, long cb2Br,
    float* __restrict__ Mb,
    const float* __restrict__ bias, long biasBr)
{
    const int br = blockIdx.z;
    Ab += (long)br * aBr;
    Bt += (long)br * bBr;
    if (MODE == 3) { C0 += (long)br * c0Br; C1 += (long)br * c1Br;
                     bias += (long)br * biasBr; }
    if (MODE == 0) { Cb += (long)br * cbBr; Cb2 += (long)br * cb2Br; }
    if (MODE == 1) { Mb += (long)br * (Bk * DMODEL); }
    const int m0 = blockIdx.x * 64, n0 = blockIdx.y * 64;
    __shared__ __align__(16) unsigned short As[8 * 64 * 8];  // [kch][m][8]
    __shared__ __align__(16) unsigned short Bs[8 * 64 * 8];  // [kch][n][8]
    const int tid = threadIdx.x;
    const int lane = tid & 63, w = tid >> 6;
    const int wm = w >> 1, wn = w & 1;
    const int quad = lane >> 4, l15 = lane & 15;
    f32x4 acc00 = {0,0,0,0}, acc01 = {0,0,0,0}, acc10 = {0,0,0,0}, acc11 = {0,0,0,0};
    for (int kc = 0; kc < K; kc += 64) {
        #pragma unroll
        for (int it = 0; it < 2; ++it) {
            const int c = tid + it * 256;
            const int r = c & 63, kch = c >> 6;
            *(u16x8*)&As[(kch * 64 + r) * 8] =
                *(const u16x8*)(Ab + (long)(m0 + r) * K + kc + kch * 8);
            *(u16x8*)&Bs[(kch * 64 + r) * 8] =
                *(const u16x8*)(Bt + (long)(n0 + r) * K + kc + kch * 8);
        }
        __syncthreads();
        #pragma unroll
        for (int k0 = 0; k0 < 64; k0 += 32) {
            const int kch = (k0 >> 3) + quad;
            bf16x8 a0 = *(const bf16x8*)&As[(kch * 64 + wm * 32 +      l15) * 8];
            bf16x8 a1 = *(const bf16x8*)&As[(kch * 64 + wm * 32 + 16 + l15) * 8];
            bf16x8 b0 = *(const bf16x8*)&Bs[(kch * 64 + wn * 32 +      l15) * 8];
            bf16x8 b1 = *(const bf16x8*)&Bs[(kch * 64 + wn * 32 + 16 + l15) * 8];
            acc00 = __builtin_amdgcn_mfma_f32_16x16x32_bf16(a0, b0, acc00, 0, 0, 0);
            acc01 = __builtin_amdgcn_mfma_f32_16x16x32_bf16(a0, b1, acc01, 0, 0, 0);
            acc10 = __builtin_amdgcn_mfma_f32_16x16x32_bf16(a1, b0, acc10, 0, 0, 0);
            acc11 = __builtin_amdgcn_mfma_f32_16x16x32_bf16(a1, b1, acc11, 0, 0, 0);
        }
        __syncthreads();
    }
    if (MODE == 1) {
        float s0 = 0.f, s1 = 0.f;
        #pragma unroll
        for (int r = 0; r < 4; ++r) { s0 += acc00[r] + acc10[r];
                                      s1 += acc01[r] + acc11[r]; }
        const int bidx = m0 >> 10;
        atomicAdd(&Mb[bidx * DMODEL + n0 + wn * 32 + l15], s0);
        atomicAdd(&Mb[bidx * DMODEL + n0 + wn * 32 + 16 + l15], s1);
        return;
    }
    #pragma unroll
    for (int e = 0; e < 4; ++e) {
        f32x4 a = (e == 0) ? acc00 : (e == 1) ? acc01 : (e == 2) ? acc10 : acc11;
        const int msub = (e >> 1) * 16, nsub = (e & 1) * 16;
        const int col = n0 + wn * 32 + nsub + l15;
        #pragma unroll
        for (int r = 0; r < 4; ++r) {
            const int row = m0 + wm * 32 + msub + quad * 4 + r;
            const float v = a[r];
            if (MODE == 0) {
                if (n0 < 256) Cb[(long)row * 256 + col] = f2b(v);
                else          Cb2[(long)row * 256 + (col - 256)] = f2b(siluf(v));
            } else {
                if (col < 256)      C0[(long)row * 256 + col] = softplusf(v + bias[col]);
                else if (col < 288) C1[(long)row * 32 + (col - 256)] = v;
            }
        }
    }
}

// ---------------------------------------------------------------------------
// fp32 weight-product GEMM (once): Wtmp[p*4+br] = Wout_p @ Win_{p+1}
// [256][512], K=128.  Block (0,0,0) also zeroes the mean buffer region.
// ---------------------------------------------------------------------------
__global__ __launch_bounds__(256) void sgemmW_k(
    const float* __restrict__ Wout, const float* __restrict__ Win,
    float* __restrict__ Wtmp, unsigned* __restrict__ zbuf)
{
    if (blockIdx.x == 0 && blockIdx.y == 0 && blockIdx.z == 0) {
        for (int i = threadIdx.x; i < 4096; i += 256) zbuf[i] = 0u;
    }
    const int z = blockIdx.z, p = z >> 2, br = z & 3;
    const float* A  = Wout + (long)(br * NLAY + p) * DINNER * DMODEL;
    const float* Bw = Win  + (long)(br * NLAY + p + 1) * DMODEL * 512;
    float* C = Wtmp + (long)z * DINNER * 512;
    const int m0 = blockIdx.x * 64, n0 = blockIdx.y * 64;
    __shared__ float As[32][68];
    __shared__ float Bs[32][68];
    const int tid = threadIdx.x;
    const int tx = tid & 15, ty = tid >> 4;
    float acc[4][4] = {};
    for (int kc = 0; kc < DMODEL; kc += 32) {
        #pragma unroll
        for (int it = 0; it < 2; ++it) {
            int id = tid + it * 256;
            int r = id >> 3, c4 = (id & 7) << 2;
            float4 v = *(const float4*)(A + (long)(m0 + r) * DMODEL + kc + c4);
            As[c4+0][r] = v.x; As[c4+1][r] = v.y; As[c4+2][r] = v.z; As[c4+3][r] = v.w;
            int rb = id >> 4, cb = (id & 15) << 2;
            *(float4*)&Bs[rb][cb] = *(const float4*)(Bw + (long)(kc + rb) * 512 + n0 + cb);
        }
        __syncthreads();
        #pragma unroll
        for (int kk = 0; kk < 32; ++kk) {
            float4 a4 = *(const float4*)&As[kk][ty << 2];
            float4 b4 = *(const float4*)&Bs[kk][tx << 2];
            float av[4] = {a4.x, a4.y, a4.z, a4.w};
            float bv[4] = {b4.x, b4.y, b4.z, b4.w};
            #pragma unroll
            for (int i = 0; i < 4; ++i)
                #pragma unroll
                for (int j = 0; j < 4; ++j)
                    acc[i][j] = fmaf(av[i], bv[j], acc[i][j]);
        }
        __syncthreads();
    }
    #pragma unroll
    for (int i = 0; i < 4; ++i) {
        int row = m0 + (ty << 2) + i, col = n0 + (tx << 2);
        float4 v4; v4.x = acc[i][0]; v4.y = acc[i][1]; v4.z = acc[i][2]; v4.w = acc[i][3];
        *(float4*)(C + (long)row * 512 + col) = v4;
    }
}

// ---------------------------------------------------------------------------
// devices for prepAll
// ---------------------------------------------------------------------------
__device__ void transposeTile(const float* __restrict__ W,
                              unsigned short* __restrict__ o,
                              int Kd, int Nd, int n0, int k0, float* smem)
{
    float (*tile)[65] = (float(*)[65])smem;
    const int t = threadIdx.x;
    #pragma unroll
    for (int i = 0; i < 16; ++i) {
        int idx = t + i * 256;
        int kl = idx >> 6, nl = idx & 63;
        tile[kl][nl] = W[(long)(k0 + kl) * Nd + n0 + nl];
    }
    __syncthreads();
    #pragma unroll
    for (int i = 0; i < 16; ++i) {
        int idx = t + i * 256;
        int nl = idx >> 6, kl = idx & 63;
        o[(long)(n0 + nl) * Kd + k0 + kl] = f2b(tile[kl][nl]);
    }
}

// ---------------------------------------------------------------------------
// prepAll: one dispatch for all weight panels + input projection.
// Flat blockIdx.x sections:
//   [0,64):    Win0T  = (W_in[br][0])^T          -> bf16 [512][128]
//   [64,320):  WfT    = Wtmp^T                   -> bf16 [8][512][256]
//   [320,352): Wo2T   = (W_out[br][2])^T         -> bf16 [128][256]
//   [352,4192): WcT   dt|bc fused panel           -> bf16 [12][320][256]
//   [4192,4704): proj  h_bf = bf16(x @ W_ip + b)  (fp32 K=32 GEMM)
// ---------------------------------------------------------------------------
__global__ __launch_bounds__(256) void prepAll_k(
    const float* __restrict__ W_in, const float* __restrict__ Wtmp,
    const float* __restrict__ W_out,
    const float* __restrict__ W_x, const float* __restrict__ W_dt,
    const float* __restrict__ X0, const float* __restrict__ X1,
    const float* __restrict__ X2, const float* __restrict__ X3,
    const float* __restrict__ W_ip, const float* __restrict__ b_ip,
    unsigned short* __restrict__ Win0T, unsigned short* __restrict__ WfT,
    unsigned short* __restrict__ Wo2T, unsigned short* __restrict__ WcT,
    unsigned short* __restrict__ h_bf)
{
    __shared__ float smem[32 * 68 * 2];
    const int id = blockIdx.x;
    if (id < 64) {
        int br = id >> 4, rem = id & 15;
        int nt = rem & 7, kt = rem >> 3;
        transposeTile(W_in + (long)br * NLAY * DMODEL * 512,
                      Win0T + (long)br * 512 * DMODEL,
                      DMODEL, 512, nt * 64, kt * 64, smem);
    } else if (id < 320) {
        int id2 = id - 64;
        int z = id2 >> 5, rem = id2 & 31;
        int nt = rem & 7, kt = rem >> 3;
        transposeTile(Wtmp + (long)z * DINNER * 512,
                      WfT + (long)z * 512 * DINNER,
                      DINNER, 512, nt * 64, kt * 64, smem);
    } else if (id < 352) {
        int id3 = id - 320;
        int br = id3 >> 3, rem = id3 & 7;
        int nt = rem & 1, kt = rem >> 1;
        transposeTile(W_out + ((long)br * NLAY + 2) * DINNER * DMODEL,
                      Wo2T + (long)br * DMODEL * DINNER,
                      DINNER, DMODEL, nt * 64, kt * 64, smem);
    } else if (id < 4192) {
        int id4 = id - 352;
        int bl = id4 / NWB, n = id4 % NWB;
        const int k = threadIdx.x;
        const float* WxP = W_x + (long)bl * DINNER * 40;
        float v;
        if (n < 256) {
            const float* WdtP = W_dt + (long)bl * DTRANK * DINNER;
            float s = 0.f;
            #pragma unroll
            for (int r = 0; r < 8; ++r)
                s = fmaf(WxP[k * 40 + r], WdtP[r * DINNER + n], s);
            v = s;
        } else if (n < 288) {
            v = WxP[k * 40 + 8 + (n - 256)];
        } else {
            v = 0.f;
        }
        WcT[(long)bl * NWB * DINNER + (long)n * DINNER + k] = f2b(v);
    } else {
        // ---- input projection section ----
        int id5 = id - 4192;
        int br = id5 >> 7, rem = id5 & 127;
        int m0 = (rem & 63) * 64, n0 = (rem >> 6) * 64;
        const float* A = (br == 1) ? X1 : (br == 2) ? X2 : (br == 3) ? X3 : X0;
        const float* Bw = W_ip + (long)br * DIN * DMODEL;
        const float* bias = b_ip + (long)br * DMODEL;
        unsigned short* Cb = h_bf + (long)br * BT * DMODEL;
        float (*As)[68] = (float(*)[68])smem;
        float (*Bs)[68] = (float(*)[68])(smem + 32 * 68);
        const int tid = threadIdx.x;
        const int tx = tid & 15, ty = tid >> 4;
        float acc[4][4] = {};
        #pragma unroll
        for (int it = 0; it < 2; ++it) {
            int idd = tid + it * 256;
            int r = idd >> 3, c4 = (idd & 7) << 2;
            float4 v = *(const float4*)(A + (long)(m0 + r) * DIN + c4);
            As[c4+0][r] = v.x; As[c4+1][r] = v.y; As[c4+2][r] = v.z; As[c4+3][r] = v.w;
            int rb = idd >> 4, cb = (idd & 15) << 2;
            *(float4*)&Bs[rb][cb] = *(const float4*)(Bw + (long)rb * DMODEL + n0 + cb);
        }
        __syncthreads();
        #pragma unroll
        for (int kk = 0; kk < 32; ++kk) {
            float4 a4 = *(const float4*)&As[kk][ty << 2];
            float4 b4 = *(const float4*)&Bs[kk][tx << 2];
            float av[4] = {a4.x, a4.y, a4.z, a4.w};
            float bv[4] = {b4.x, b4.y, b4.z, b4.w};
            #pragma unroll
            for (int i = 0; i < 4; ++i)
                #pragma unroll
                for (int j = 0; j < 4; ++j)
                    acc[i][j] = fmaf(av[i], bv[j], acc[i][j]);
        }
        const int col = n0 + (tx << 2);
        #pragma unroll
        for (int i = 0; i < 4; ++i) {
            const int row = m0 + (ty << 2) + i;
            #pragma unroll
            for (int j = 0; j < 4; ++j)
                Cb[(long)row * DMODEL + col + j] = f2b(acc[i][j] + bias[col + j]);
        }
    }
}

// ---------------------------------------------------------------------------
// Depthwise causal conv (4 taps) + bias + silu: bf16 in -> bf16 out.
// ---------------------------------------------------------------------------
__global__ __launch_bounds__(256) void conv_k(
    const unsigned short* __restrict__ xp, const float* __restrict__ cw,
    const float* __restrict__ cb, unsigned short* __restrict__ xcb, int layer)
{
    const int br = blockIdx.y;
    const long base = (long)br * BT * DINNER;
    const int idx = blockIdx.x * 256 + threadIdx.x;
    const int d = idx & (DINNER - 1);
    const int row = idx >> 8;
    const int t = row & (Tk - 1);
    const float4 w4 = *(const float4*)(cw + ((long)(br * NLAY + layer) * DINNER + d) * 4);
    const float wv[4] = {w4.x, w4.y, w4.z, w4.w};
    float acc = cb[(br * NLAY + layer) * DINNER + d];
    const unsigned short* xpb = xp + base + idx;
    #pragma unroll
    for (int k = 0; k < 4; ++k) {
        int tt = t + k - 3;
        if (tt >= 0) acc = fmaf(b2f(xpb[(long)(k - 3) * DINNER]), wv[k], acc);
    }
    xcb[base + idx] = f2b(siluf(acc));
}

// ---------------------------------------------------------------------------
// Scan pass 1: per-chunk local recurrence from h=0 -> record (h_end[16], sumdt).
// (Inter-dispatch producer; round-9 proven structure.)
// ---------------------------------------------------------------------------
__global__ __launch_bounds__(256) void scan1_k(
    const float* __restrict__ dtb, const unsigned short* __restrict__ xcb,
    const float* __restrict__ bcb, const float* __restrict__ Alog,
    float* __restrict__ recbuf, int layer)
{
    const int c = blockIdx.x, b = blockIdx.y, br = blockIdx.z;
    const int d = threadIdx.x;
    const float* Ap = Alog + ((long)(br * NLAY + layer) * DINNER + d) * DSTATE;
    float Aa[16];
    bool pw = true;
    #pragma unroll
    for (int s = 0; s < 16; ++s) {
        Aa[s] = -__expf(Ap[s]);
        pw = pw && (fabsf(Aa[s] + (float)(s + 1)) < 1e-3f);
    }
    const long rbase = (long)br * BT + (long)b * Tk + (long)c * LCH;
    const float* dtp = dtb + rbase * DINNER + d;
    const unsigned short* xcp = xcb + rbase * DINNER + d;
    __shared__ float bcs[LCH * 32];
    {
        const float4* g = (const float4*)(bcb + rbase * 32);
        float4* l = (float4*)bcs;
        l[d] = g[d]; l[d + 256] = g[d + 256];
    }
    float dtc[UF], xcc[UF];
    #pragma unroll
    for (int u = 0; u < UF; ++u) {
        dtc[u] = dtp[(long)u * DINNER];
        xcc[u] = b2f(xcp[(long)u * DINNER]);
    }
    __syncthreads();
    float h[16];
    #pragma unroll
    for (int s = 0; s < 16; ++s) h[s] = 0.f;
    float sumdt = 0.f;
    for (int base = 0; base < LCH; base += UF) {
        const int nb = (base + UF < LCH) ? base + UF : base;
        float dtn[UF], xcn[UF];
        #pragma unroll
        for (int u = 0; u < UF; ++u) {
            dtn[u] = dtp[(long)(nb + u) * DINNER];
            xcn[u] = b2f(xcp[(long)(nb + u) * DINNER]);
        }
        #pragma unroll
        for (int u = 0; u < UF; ++u) {
            const int t = base + u;
            const float dtv = dtc[u];
            const float dtxc = dtv * xcc[u];
            sumdt += dtv;
            float dA[16];
            if (pw) dA_pow(__expf(-dtv), dA);
            else    dA_exp(dtv, Aa, dA);
            const float* bcT = bcs + t * 32;
            #pragma unroll
            for (int s = 0; s < 16; ++s)
                h[s] = fmaf(dA[s], h[s], dtxc * bcT[s]);
        }
        #pragma unroll
        for (int u = 0; u < UF; ++u) { dtc[u] = dtn[u]; xcc[u] = xcn[u]; }
    }
    float* sb = recbuf + (((long)(br * 4 + b) * (NCH - 1) + c) * 17) * 256 + d;
    #pragma unroll
    for (int s = 0; s < 16; ++s) sb[s * 256] = h[s];
    sb[16 * 256] = sumdt;
}

// ---------------------------------------------------------------------------
// Scan pass 3: fold preceding records into carry (prefetch-pipelined), then
// local recurrence; yz = (y + Dp*xc)*silu(z) -> bf16.  (Round-9 proven.)
// ---------------------------------------------------------------------------
__global__ __launch_bounds__(256) void scan3_k(
    const float* __restrict__ dtb, const unsigned short* __restrict__ xcb,
    const float* __restrict__ bcb, const unsigned short* __restrict__ zb,
    const float* __restrict__ Alog, const float* __restrict__ Dpar,
    const float* __restrict__ recbuf, unsigned short* __restrict__ yzb, int layer)
{
    const int c = blockIdx.x, b = blockIdx.y, br = blockIdx.z;
    const int d = threadIdx.x;
    const float* Ap = Alog + ((long)(br * NLAY + layer) * DINNER + d) * DSTATE;
    float Aa[16];
    bool pw = true;
    #pragma unroll
    for (int s = 0; s < 16; ++s) {
        Aa[s] = -__expf(Ap[s]);
        pw = pw && (fabsf(Aa[s] + (float)(s + 1)) < 1e-3f);
    }
    float h[16];
    #pragma unroll
    for (int s = 0; s < 16; ++s) h[s] = 0.f;
    if (c > 0) {
        const float* recB = recbuf + ((long)(br * 4 + b) * (NCH - 1)) * 17 * 256 + d;
        float rh[16], rs;
        #pragma unroll
        for (int s = 0; s < 16; ++s) rh[s] = recB[s * 256];
        rs = recB[16 * 256];
        for (int cc = 0; cc < c; ++cc) {
            float nh[16], ns = 0.f;
            if (cc + 1 < c) {
                const float* r2 = recB + (long)(cc + 1) * 17 * 256;
                #pragma unroll
                for (int s = 0; s < 16; ++s) nh[s] = r2[s * 256];
                ns = r2[16 * 256];
            } else {
                #pragma unroll
                for (int s = 0; s < 16; ++s) nh[s] = 0.f;
            }
            float P[16];
            if (pw) dA_pow(__expf(-rs), P);
            else    dA_exp(rs, Aa, P);
            #pragma unroll
            for (int s = 0; s < 16; ++s) h[s] = fmaf(h[s], P[s], rh[s]);
            #pragma unroll
            for (int s = 0; s < 16; ++s) rh[s] = nh[s];
            rs = ns;
        }
    }
    const float Dp = Dpar[(br * NLAY + layer) * DINNER + d];
    const long rbase = (long)br * BT + (long)b * Tk + (long)c * LCH;
    const float* dtp = dtb + rbase * DINNER + d;
    const unsigned short* xcp = xcb + rbase * DINNER + d;
    const unsigned short* zp  = zb  + rbase * DINNER + d;
    unsigned short* yp = yzb + rbase * DINNER + d;
    __shared__ float bcs[LCH * 32];
    {
        const float4* g = (const float4*)(bcb + rbase * 32);
        float4* l = (float4*)bcs;
        l[d] = g[d]; l[d + 256] = g[d + 256];
    }
    float dtc[UF], xcc[UF], zc[UF];
    #pragma unroll
    for (int u = 0; u < UF; ++u) {
        dtc[u] = dtp[(long)u * DINNER];
        xcc[u] = b2f(xcp[(long)u * DINNER]);
        zc[u]  = b2f(zp[(long)u * DINNER]);
    }
    __syncthreads();
    for (int base = 0; base < LCH; base += UF) {
        const int nb = (base + UF < LCH) ? base + UF : base;
        float dtn[UF], xcn[UF], zn[UF];
        #pragma unroll
        for (int u = 0; u < UF; ++u) {
            dtn[u] = dtp[(long)(nb + u) * DINNER];
            xcn[u] = b2f(xcp[(long)(nb + u) * DINNER]);
            zn[u]  = b2f(zp[(long)(nb + u) * DINNER]);
        }
        #pragma unroll
        for (int u = 0; u < UF; ++u) {
            const int t = base + u;
            const float dtv = dtc[u], xcv = xcc[u];
            const float dtxc = dtv * xcv;
            float dA[16];
            if (pw) dA_pow(__expf(-dtv), dA);
            else    dA_exp(dtv, Aa, dA);
            const float* bcT = bcs + t * 32;
            #pragma unroll
            for (int s = 0; s < 16; ++s)
                h[s] = fmaf(dA[s], h[s], dtxc * bcT[s]);
            float y0 = 0.f, y1 = 0.f, y2 = 0.f, y3 = 0.f;
            #pragma unroll
            for (int s = 0; s < 16; s += 4) {
                y0 = fmaf(h[s+0], bcT[16+s+0], y0);
                y1 = fmaf(h[s+1], bcT[16+s+1], y1);
                y2 = fmaf(h[s+2], bcT[16+s+2], y2);
                y3 = fmaf(h[s+3], bcT[16+s+3], y3);
            }
            const float y = (y0 + y1) + (y2 + y3) + Dp * xcv;
            yp[(long)t * DINNER] = f2b(y * zc[u]);
        }
        #pragma unroll
        for (int u = 0; u < UF; ++u) { dtc[u] = dtn[u]; xcc[u] = xcn[u]; zc[u] = zn[u]; }
    }
}

// ---------------------------------------------------------------------------
// final: z_t = mean(h) @ W_op + b_op, then Lorentz epilogue.
// ---------------------------------------------------------------------------
__global__ __launch_bounds__(64) void final_k(
    const float* __restrict__ Mb, const float* __restrict__ Wop,
    const float* __restrict__ bop, float* __restrict__ out,
    const float* __restrict__ eff)
{
    __shared__ float hm[NBR * Bk * DMODEL];   // 2048
    __shared__ float zts[NBR * Bk * EMBEDk];  // 1024
    __shared__ float us[NBR][Bk][EMBEDk];
    const int t = threadIdx.x;
    for (int i = t; i < NBR * Bk * DMODEL; i += 64) hm[i] = Mb[i] * (1.0f / Tk);
    __syncthreads();
    for (int br = 0; br < NBR; ++br) {
        const float* wp = Wop + (long)br * DMODEL * EMBEDk + t;
        const float bb = bop[br * EMBEDk + t];
        for (int b = 0; b < Bk; ++b) {
            const float* hmp = &hm[(br * Bk + b) * DMODEL];
            float acc = bb;
            for (int k = 0; k < DMODEL; ++k) acc = fmaf(hmp[k], wp[k * EMBEDk], acc);
            out[(br * Bk + b) * EMBEDk + t] = acc;
            zts[(br * Bk + b) * EMBEDk + t] = acc;
        }
    }
    __syncthreads();
    const float es = tanhf(eff[0]);
    if (t < 16) {
        const int br = t >> 2, b = t & 3;
        const float* z = &zts[(br * Bk + b) * EMBEDk];
        float n2 = 0.f;
        for (int e = 0; e < EMBEDk; ++e) { float v = z[e] * es; n2 = fmaf(v, v, n2); }
        const float n  = sqrtf(n2);
        const float nc = fminf(fmaxf(n, EPSF), MAXNF);
        const float sc = nc / fmaxf(n, EPSF);
        const float sh = sinhf(nc) / nc;
        const float fac = es * sc * sh;
        float* zh = out + 1024 + br * (Bk * (EMBEDk + 1)) + b * (EMBEDk + 1);
        float sp2 = 0.f;
        for (int e = 0; e < EMBEDk; ++e) {
            float spv = z[e] * fac;
            sp2 = fmaf(spv, spv, sp2);
            zh[1 + e] = spv;
            us[br][b][e] = spv;
        }
        const float t0 = sqrtf(1.f + sp2);
        zh[0] = t0;
        const float dd  = acoshf(fmaxf(t0, 1.f + EPSF));
        const float spn = fmaxf(sqrtf(sp2), EPSF);
        const float rr  = dd / spn;
        for (int e = 0; e < EMBEDk; ++e) us[br][b][e] *= rr;
    }
    __syncthreads();
    if (t < 4) {
        const int b = t;
        float ct[EMBEDk];
        float* cto = out + 2064 + b * EMBEDk;
        for (int e = 0; e < EMBEDk; ++e) {
            float v = us[0][b][e] + us[1][b][e] + us[2][b][e] + us[3][b][e];
            ct[e] = v; cto[e] = v;
        }
        float n2 = 0.f;
        for (int e = 0; e < EMBEDk; ++e) { float v = ct[e] * es; n2 = fmaf(v, v, n2); }
        const float n  = sqrtf(n2);
        const float nc = fminf(fmaxf(n, EPSF), MAXNF);
        const float sc = nc / fmaxf(n, EPSF);
        const float sh = sinhf(nc) / nc;
        const float fac = es * sc * sh;
        float* ch = out + 2320 + b * (EMBEDk + 1);
        float sp2 = 0.f;
        for (int e = 0; e < EMBEDk; ++e) {
            float spv = ct[e] * fac;
            sp2 = fmaf(spv, spv, sp2);
            ch[1 + e] = spv;
        }
        ch[0] = sqrtf(1.f + sp2);
    }
}

extern "C" void kernel_launch(void* const* d_in, const int* in_sizes, int n_in,
                              void* d_out, int out_size, void* d_ws, size_t ws_size,
                              hipStream_t stream)
{
    const float* X0 = (const float*)d_in[0];
    const float* X1 = (const float*)d_in[1];
    const float* X2 = (const float*)d_in[2];
    const float* X3 = (const float*)d_in[3];
    const float* W_ip   = (const float*)d_in[4];
    const float* b_ip   = (const float*)d_in[5];
    const float* W_in   = (const float*)d_in[6];
    const float* conv_w = (const float*)d_in[7];
    const float* conv_b = (const float*)d_in[8];
    const float* W_x    = (const float*)d_in[9];
    const float* W_dt   = (const float*)d_in[10];
    const float* b_dt   = (const float*)d_in[11];
    const float* A_log  = (const float*)d_in[12];
    const float* D_par  = (const float*)d_in[13];
    const float* W_out  = (const float*)d_in[14];
    const float* W_op   = (const float*)d_in[15];
    const float* b_op   = (const float*)d_in[16];
    const float* eff    = (const float*)d_in[17];
    float* out = (float*)d_out;
    float* ws  = (float*)d_ws;

    // ---- workspace layout (~60 MB) ----
    float* meanb  = ws + 1024;                            // [br][b][128] = 2048 f32
    float* buf_dt = ws + 4096;                            // 4.19M f32
    float* buf_bc = buf_dt + (long)NBR * BT * DINNER;     // 0.52M f32
    float* recbuf = buf_bc + (long)NBR * BT * 32;         // 16*15*17*256 f32
    float* Wtmp   = recbuf + (long)16 * (NCH - 1) * 17 * 256;  // 8*256*512 f32
    unsigned short* h_bf  = (unsigned short*)(Wtmp + (long)8 * DINNER * 512);
    unsigned short* xp_bf = h_bf  + (long)NBR * BT * DMODEL;
    unsigned short* z_bf  = xp_bf + (long)NBR * BT * DINNER;
    unsigned short* xc_bf = z_bf  + (long)NBR * BT * DINNER;
    unsigned short* yz_bf = xc_bf + (long)NBR * BT * DINNER;
    unsigned short* Win0T = yz_bf + (long)NBR * BT * DINNER;
    unsigned short* WfT   = Win0T + (long)NBR * 512 * DMODEL;
    unsigned short* Wo2T  = WfT   + (long)8 * 512 * DINNER;
    unsigned short* WcT   = Wo2T  + (long)NBR * DMODEL * DINNER;

    // 1) Wtmp = Wout_p @ Win_{p+1}  (+ zero mean buffer region)
    sgemmW_k<<<dim3(4, 8, 8), 256, 0, stream>>>(W_out, W_in, Wtmp, (unsigned*)ws);
    // 2) all weight panels + input projection
    prepAll_k<<<4704, 256, 0, stream>>>(
        W_in, Wtmp, W_out, W_x, W_dt, X0, X1, X2, X3, W_ip, b_ip,
        Win0T, WfT, Wo2T, WcT, h_bf);

    for (int l = 0; l < NLAY; ++l) {
        // xz: l==0: h_bf @ Win_0 (K=128); else yz_bf @ (Wout_{l-1}·Win_l) (K=256)
        if (l == 0) {
            bgemm_k<0><<<dim3(BT / 64, 8, NBR), 256, 0, stream>>>(
                h_bf, (long)BT * DMODEL, DMODEL, Win0T, (long)512 * DMODEL,
                nullptr, 0, nullptr, 0,
                xp_bf, (long)BT * DINNER, z_bf, (long)BT * DINNER,
                nullptr, nullptr, 0);
        } else {
            bgemm_k<0><<<dim3(BT / 64, 8, NBR), 256, 0, stream>>>(
                yz_bf, (long)BT * DINNER, DINNER,
                WfT + (long)(l - 1) * 4 * 512 * DINNER, (long)512 * DINNER,
                nullptr, 0, nullptr, 0,
                xp_bf, (long)BT * DINNER, z_bf, (long)BT * DINNER,
                nullptr, nullptr, 0);
        }
        // depthwise conv + silu
        conv_k<<<dim3((BT * DINNER) / 256, NBR), 256, 0, stream>>>(
            xp_bf, conv_w, conv_b, xc_bf, l);
        // dt|bc fused GEMM
        bgemm_k<3><<<dim3(BT / 64, NWB / 64, NBR), 256, 0, stream>>>(
            xc_bf, (long)BT * DINNER, DINNER,
            WcT + (long)l * NWB * DINNER, (long)NLAY * NWB * DINNER,
            buf_dt, (long)BT * DINNER, buf_bc, (long)BT * 32,
            nullptr, 0, nullptr, 0,
            nullptr, b_dt + l * DINNER, (long)NLAY * DINNER);
        // chunked scan (two dispatches, inter-kernel coherence -> safe)
        scan1_k<<<dim3(NCH - 1, Bk, NBR), 256, 0, stream>>>(
            buf_dt, xc_bf, buf_bc, A_log, recbuf, l);
        scan3_k<<<dim3(NCH, Bk, NBR), 256, 0, stream>>>(
            buf_dt, xc_bf, buf_bc, z_bf, A_log, D_par, recbuf, yz_bf, l);
        // final layer: mean(yz @ Wout_2) via atomics
        if (l == NLAY - 1) {
            bgemm_k<1><<<dim3(BT / 64, DMODEL / 64, NBR), 256, 0, stream>>>(
                yz_bf, (long)BT * DINNER, DINNER,
                Wo2T, (long)DMODEL * DINNER,
                nullptr, 0, nullptr, 0, nullptr, 0, nullptr, 0,
                meanb, nullptr, 0);
        }
    }

    final_k<<<1, 64, 0, stream>>>(meanb, W_op, b_op, out, eff);
}